// Round 12
// baseline (339.035 us; speedup 1.0000x reference)
//
#include <hip/hip_runtime.h>
#include <hip/hip_bf16.h>

#define NN 100000
#define NROWS 100032      // NN rounded up to 64; rows >= NN are zero (gather sentinel)
#define NE 1600000
#define DD 128
#define NBUK 196          // ceil(100000 / 512) buckets of 512 target nodes
#define F1_BLOCKS 256
#define F3_BLOCKS 256

typedef unsigned short ushort_t;
typedef unsigned int uint_t;
typedef unsigned long long uint64_t_;
typedef __attribute__((ext_vector_type(8))) short bf16x8;
typedef __attribute__((ext_vector_type(4))) float f32x4;

__device__ __forceinline__ ushort_t bf16rne(float f) {
    uint_t u = __float_as_uint(f);
    u += 0x7FFF + ((u >> 16) & 1);
    return (ushort_t)(u >> 16);
}
__device__ __forceinline__ float bfLo(uint_t u) { return __uint_as_float(u << 16); }
__device__ __forceinline__ float bfHi(uint_t u) { return __uint_as_float(u & 0xFFFF0000u); }

// ---------------- CSR build (bucketed counting sort) ----------------

__global__ __launch_bounds__(256) void f1_bucket_count(const int* __restrict__ col,
                                                       int* __restrict__ bukCount) {
    __shared__ int hist[NBUK];
    for (int t = threadIdx.x; t < NBUK; t += 256) hist[t] = 0;
    __syncthreads();
    const int epb = (NE + F1_BLOCKS - 1) / F1_BLOCKS;
    const int e0 = blockIdx.x * epb;
    const int e1 = min(e0 + epb, NE);
    for (int e = e0 + threadIdx.x; e < e1; e += 256)
        atomicAdd(&hist[col[e] >> 9], 1);
    __syncthreads();
    for (int t = threadIdx.x; t < NBUK; t += 256)
        if (hist[t]) atomicAdd(&bukCount[t], hist[t]);
}

__global__ void f2_bucket_scan(const int* __restrict__ bukCount,
                               int* __restrict__ bukBase,
                               int* __restrict__ bukCursor,
                               int* __restrict__ offsets) {
    __shared__ int s[256];
    const int t = threadIdx.x;
    int v = (t < NBUK) ? bukCount[t] : 0;
    s[t] = v;
    __syncthreads();
    for (int off = 1; off < 256; off <<= 1) {
        int tmp = (t >= off) ? s[t - off] : 0;
        __syncthreads();
        s[t] += tmp;
        __syncthreads();
    }
    int excl = s[t] - v;
    if (t < NBUK) { bukBase[t] = excl; bukCursor[t] = excl; }
    if (t == 255) { bukBase[NBUK] = s[255]; offsets[NN] = s[255]; }
}

// per-wave LDS histograms; ebuf packed as (row<<9)|col_local
__global__ __launch_bounds__(256) void f3_scatter(const int* __restrict__ row,
                                                  const int* __restrict__ col,
                                                  int* __restrict__ bukCursor,
                                                  int* __restrict__ ebuf) {
    __shared__ int hist[4][NBUK];
    __shared__ int base[4][NBUK];
    const int t = threadIdx.x;
    const int w = t >> 6;
    const int lane = t & 63;
    for (int i = t; i < 4 * NBUK; i += 256) (&hist[0][0])[i] = 0;
    __syncthreads();
    const int epb = (NE + F3_BLOCKS - 1) / F3_BLOCKS;
    const int e0 = blockIdx.x * epb;
    const int e1 = min(e0 + epb, NE);
    const int wepb = (e1 - e0 + 3) >> 2;
    const int we0 = e0 + w * wepb;
    const int we1 = min(we0 + wepb, e1);
    for (int e = we0 + lane; e < we1; e += 64)
        atomicAdd(&hist[w][col[e] >> 9], 1);
    __syncthreads();
    if (t < NBUK) {
        int h0 = hist[0][t], h1 = hist[1][t], h2 = hist[2][t], h3 = hist[3][t];
        int tot = h0 + h1 + h2 + h3;
        int g = tot ? atomicAdd(&bukCursor[t], tot) : 0;
        base[0][t] = g; base[1][t] = g + h0;
        base[2][t] = g + h0 + h1; base[3][t] = g + h0 + h1 + h2;
        hist[0][t] = 0; hist[1][t] = 0; hist[2][t] = 0; hist[3][t] = 0;
    }
    __syncthreads();
    for (int e = we0 + lane; e < we1; e += 64) {
        int c = col[e];
        int b = c >> 9;
        int r = atomicAdd(&hist[w][b], 1);
        ebuf[base[w][b] + r] = (row[e] << 9) | (c & 511);
    }
}

__global__ __launch_bounds__(256) void f4_finalize(const int* __restrict__ ebuf,
                                                   const int* __restrict__ bukBase,
                                                   int* __restrict__ offsets,
                                                   float* __restrict__ dis,
                                                   int* __restrict__ csr_src) {
    __shared__ int cnt[512];
    __shared__ int cur[512];
    __shared__ int s[256];
    const int t = threadIdx.x;
    const int colBase = blockIdx.x << 9;
    const int ncols = min(512, NN - colBase);
    cnt[t] = 0; cnt[t + 256] = 0;
    __syncthreads();
    const int eb0 = bukBase[blockIdx.x];
    const int eb1 = bukBase[blockIdx.x + 1];
    for (int e = eb0 + t; e < eb1; e += 256)
        atomicAdd(&cnt[ebuf[e] & 511], 1);
    __syncthreads();
    const int c0 = cnt[2 * t], c1 = cnt[2 * t + 1];
    const int psum = c0 + c1;
    s[t] = psum;
    __syncthreads();
    for (int off = 1; off < 256; off <<= 1) {
        int tmp = (t >= off) ? s[t - off] : 0;
        __syncthreads();
        s[t] += tmp;
        __syncthreads();
    }
    const int exclPair = s[t] - psum;
    const int g0 = eb0 + exclPair;
    const int g1 = g0 + c0;
    cur[2 * t] = g0; cur[2 * t + 1] = g1;
    if (2 * t < ncols)     { offsets[colBase + 2 * t]     = g0; dis[colBase + 2 * t]     = rsqrtf((float)(c0 + 1)); }
    if (2 * t + 1 < ncols) { offsets[colBase + 2 * t + 1] = g1; dis[colBase + 2 * t + 1] = rsqrtf((float)(c1 + 1)); }
    __syncthreads();
    for (int e = eb0 + t; e < eb1; e += 256) {
        int pc = ebuf[e];
        int p = atomicAdd(&cur[pc & 511], 1);
        csr_src[p] = pc >> 9;
    }
}

// ---------------- W prep: bf16 + transpose wT[l][col][k] ----------------

__global__ __launch_bounds__(256) void wt_kernel(const float* __restrict__ Ws,
                                                 ushort_t* __restrict__ wT) {
    int idx = blockIdx.x * 256 + threadIdx.x;
    if (idx >= 3 * 128 * 16) return;
    int l = idx >> 11;
    int r = idx & 2047;
    int c = r >> 4;
    int kc = r & 15;
    const float* w = Ws + l * 16384;
    ushort_t tmp[8];
#pragma unroll
    for (int e = 0; e < 8; ++e)
        tmp[e] = bf16rne(w[(kc * 8 + e) * 128 + c]);
    *(uint4*)&wT[(size_t)l * 16384 + c * 128 + kc * 8] = *(uint4*)tmp;
}

// ---------------- MFMA GEMM -> 8-plane-major Y ----------------
// Y layout: 8 planes, plane s = [NROWS][32B] = dims [s*16, s*16+16) of each row.
// Rows >= NN written as zero in every plane (gather sentinels).

template<bool XF32>
__global__ __launch_bounds__(256) void gemm_mfma(const void* __restrict__ Xv,
                                                 const ushort_t* __restrict__ wT,
                                                 const float* __restrict__ dis,
                                                 ushort_t* __restrict__ Y) {
    __shared__ short smem[128 * 136];   // 34.8 KB: W-stage, then bf16-C stage
    {
        const uint4* src = (const uint4*)wT;
        int t = threadIdx.x;
#pragma unroll
        for (int i = 0; i < 8; ++i) {
            int idx = i * 256 + t;
            int rowc = idx >> 4;
            int kc = idx & 15;
            uint4 v = src[idx];
            *(uint4*)&smem[rowc * 136 + kc * 8] = v;
        }
    }
    __syncthreads();

    const int wave = threadIdx.x >> 6;
    const int lane = threadIdx.x & 63;
    const int m = lane & 15;
    const int kg = lane >> 4;
    const int r0 = blockIdx.x * 64 + wave * 16;
    const int rowA = min(r0 + m, NN - 1);

    f32x4 acc[8];
#pragma unroll
    for (int ct = 0; ct < 8; ++ct) acc[ct] = (f32x4){0.f, 0.f, 0.f, 0.f};

#pragma unroll
    for (int ks = 0; ks < 4; ++ks) {
        bf16x8 af;
        if (XF32) {
            const float* xp = (const float*)Xv + (size_t)rowA * DD + ks * 32 + kg * 8;
            float4 f0 = *(const float4*)xp;
            float4 f1 = *(const float4*)(xp + 4);
            af[0] = (short)bf16rne(f0.x); af[1] = (short)bf16rne(f0.y);
            af[2] = (short)bf16rne(f0.z); af[3] = (short)bf16rne(f0.w);
            af[4] = (short)bf16rne(f1.x); af[5] = (short)bf16rne(f1.y);
            af[6] = (short)bf16rne(f1.z); af[7] = (short)bf16rne(f1.w);
        } else {
            const ushort_t* xp = (const ushort_t*)Xv + (size_t)rowA * DD + ks * 32 + kg * 8;
            af = *(const bf16x8*)xp;
        }
#pragma unroll
        for (int ct = 0; ct < 8; ++ct) {
            bf16x8 bf = *(const bf16x8*)&smem[(ct * 16 + m) * 136 + ks * 32 + kg * 8];
            acc[ct] = __builtin_amdgcn_mfma_f32_16x16x32_bf16(af, bf, acc[ct], 0, 0, 0);
        }
    }

    __syncthreads();   // all waves done reading W; smem becomes C-stage

    // C/D: col = ct*16 + m, row = kg*4 + rg  [m89-verified]
    ushort_t* sl = (ushort_t*)smem;          // [64 rows][132 cols]
    const int rbase = r0 + kg * 4;
    float dv[4];
#pragma unroll
    for (int rg = 0; rg < 4; ++rg) dv[rg] = dis[min(rbase + rg, NN - 1)];
#pragma unroll
    for (int ct = 0; ct < 8; ++ct) {
#pragma unroll
        for (int rg = 0; rg < 4; ++rg)
            sl[(wave * 16 + kg * 4 + rg) * 132 + ct * 16 + m] = bf16rne(acc[ct][rg] * dv[rg]);
    }

    // readback and plane-major store (8B per lane per plane)
    const int i = threadIdx.x >> 2;          // row within block tile 0..63
    const int q = threadIdx.x & 3;           // 8B chunk within 32B plane row
    const int grow = blockIdx.x * 64 + i;
    const bool ok = grow < NN;
    const ushort_t* rb = sl + i * 132;
    uint64_t_* lp2 = (uint64_t_*)Y;
#pragma unroll
    for (int s = 0; s < 8; ++s) {
        const uint_t* p = (const uint_t*)(rb + s * 16 + q * 4);
        uint64_t_ d = (uint64_t_)p[0] | ((uint64_t_)p[1] << 32);
        uint64_t_ z = ok ? d : 0ull;
        __builtin_nontemporal_store(z, &lp2[((size_t)s * NROWS + grow) * 4 + q]);
    }
}

// ---------------- aggregation (8-plane, uint2 lanes: 16 nodes x 4 lanes) ----------------
// Slice = 32B (16 dims); bid&7 = slice -> XCD (3.2 MB plane, L2-resident; R10-validated
// FETCH floor). Wave = 16 nodes x 4 lanes x 8B: one gather instr = 16 x 32B rows = 512B.
// 32 edges/node prefetched into 8 regs via the node's 4 lanes; sentinel row NN is zero.

template<bool F32OUT>
__global__ __launch_bounds__(256) void agg_kernel(const uint_t* __restrict__ lin_planes,
                                                  const int* __restrict__ offsets,
                                                  const int* __restrict__ csr_src,
                                                  const float* __restrict__ dis,
                                                  const float* __restrict__ bias,
                                                  void* __restrict__ outv) {
    const int bid  = blockIdx.x;                // 12504 blocks
    const int s    = bid & 7;                   // slice == XCD (heuristic)
    const int gblk = bid >> 3;                  // 0..1562 (64 nodes each)
    const int w    = threadIdx.x >> 6;
    const int lane = threadIdx.x & 63;
    const int g    = lane >> 2;                 // node within wave 0..15
    const int u    = lane & 3;                  // uint2 (8B) within 32B row
    const int v    = gblk * 64 + w * 16 + g;
    const int vv   = min(v, NN - 1);            // clamp (writes suppressed for v>=NN)

    const int start = offsets[vv];
    const int deg   = offsets[vv + 1] - start;

    const uint_t* plane = lin_planes + (size_t)s * (NROWS * 8);

    // prefetch 32 indices: lane u holds edges u, u+4, ..., u+28 in iv[0..7]
    int iv[8];
    {
        const int* cp = csr_src + start + u;
#pragma unroll
        for (int k = 0; k < 8; ++k) {
            int t = cp[4 * k];
            iv[k] = (u + 4 * k < deg) ? t : NN;
        }
    }

    // wave max degree to skip dead 8-edge blocks
    int wmax = deg;
    wmax = max(wmax, __shfl_xor(wmax, 4));
    wmax = max(wmax, __shfl_xor(wmax, 8));
    wmax = max(wmax, __shfl_xor(wmax, 16));
    wmax = max(wmax, __shfl_xor(wmax, 32));

    float a0 = 0.f, a1 = 0.f, a2 = 0.f, a3 = 0.f;
    const int gbase = lane & 60;                // g*4
#pragma unroll
    for (int b = 0; b < 4; ++b) {
        if (b * 8 < wmax) {
#pragma unroll
            for (int jj = 0; jj < 8; ++jj) {
                const int j = b * 8 + jj;
                int src = __shfl(iv[j >> 2], gbase + (j & 3));
                uint2 a = *(const uint2*)(plane + ((size_t)src << 3) + u * 2);
                a0 += bfLo(a.x); a1 += bfHi(a.x);
                a2 += bfLo(a.y); a3 += bfHi(a.y);
            }
        }
    }
    // self-loop
    {
        uint2 a = *(const uint2*)(plane + ((size_t)vv << 3) + u * 2);
        a0 += bfLo(a.x); a1 += bfHi(a.x);
        a2 += bfLo(a.y); a3 += bfHi(a.y);
    }
    // rare deg>32 tail (node-divergent)
    if (deg > 32) {
        for (int e = start + 32; e < start + deg; ++e) {
            int src = csr_src[e];
            uint2 a = *(const uint2*)(plane + ((size_t)src << 3) + u * 2);
            a0 += bfLo(a.x); a1 += bfHi(a.x);
            a2 += bfLo(a.y); a3 += bfHi(a.y);
        }
    }

    if (v < NN) {
        const float dv = dis[v];
        const float4 b4 = ((const float4*)bias)[s * 4 + u];
        float r0 = fmaxf(fmaf(dv, a0, b4.x), 0.f);
        float r1 = fmaxf(fmaf(dv, a1, b4.y), 0.f);
        float r2 = fmaxf(fmaf(dv, a2, b4.z), 0.f);
        float r3 = fmaxf(fmaf(dv, a3, b4.w), 0.f);
        if (F32OUT) {
            float* op = (float*)outv + (size_t)v * DD + s * 16 + u * 4;
            float2 lo = make_float2(r0, r1);
            float2 hi = make_float2(r2, r3);
            __builtin_nontemporal_store(*(const uint64_t_*)&lo, (uint64_t_*)op);
            __builtin_nontemporal_store(*(const uint64_t_*)&hi, (uint64_t_*)op + 1);
        } else {
            uint_t p0 = (uint_t)bf16rne(r0) | ((uint_t)bf16rne(r1) << 16);
            uint_t p1 = (uint_t)bf16rne(r2) | ((uint_t)bf16rne(r3) << 16);
            uint64_t_ pk = (uint64_t_)p0 | ((uint64_t_)p1 << 32);
            __builtin_nontemporal_store(pk, (uint64_t_*)((uint_t*)outv + (size_t)v * 64 + s * 8 + u * 2));
        }
    }
}

// ---------------- launch ----------------

extern "C" void kernel_launch(void* const* d_in, const int* in_sizes, int n_in,
                              void* d_out, int out_size, void* d_ws, size_t ws_size,
                              hipStream_t stream) {
    const float* x   = (const float*)d_in[0];
    const int*   ei  = (const int*)d_in[1];
    const float* Ws  = (const float*)d_in[2];
    const float* bs  = (const float*)d_in[3];

    const int* row = ei;
    const int* col = ei + NE;

    char* ws = (char*)d_ws;
    // lin planes: 8 * NROWS * 32B = 25,608,192 B (ebuf aliases low part)
    ushort_t* lin    = (ushort_t*)(ws + 0);
    int*   ebuf      = (int*)  (ws + 0);          // 6,400,000 B packed (dead before gemm)
    ushort_t* hb     = (ushort_t*)(ws + 25608192);// 25,600,000 B bf16 inter-layer h (row-major)
    float* dis       = (float*)(ws + 51208192);   // 400,000 B
    int*   offsets   = (int*)  (ws + 51608192);   // 400,004 B
    int*   csr_src   = (int*)  (ws + 52008208);   // 6,400,000 B (+124B overrun reads land in bukCount region: address-safe, values discarded)
    int*   bukCount  = (int*)  (ws + 58408208);   // 784 B
    int*   bukBase   = (int*)  (ws + 58409008);   // 788 B
    int*   bukCursor = (int*)  (ws + 58409808);   // 784 B
    ushort_t* wT     = (ushort_t*)(ws + 58410608);// 98,304 B

    (void)hipMemsetAsync(bukCount, 0, NBUK * sizeof(int), stream);
    f1_bucket_count<<<F1_BLOCKS, 256, 0, stream>>>(col, bukCount);
    f2_bucket_scan<<<1, 256, 0, stream>>>(bukCount, bukBase, bukCursor, offsets);
    f3_scatter<<<F3_BLOCKS, 256, 0, stream>>>(row, col, bukCursor, ebuf);
    f4_finalize<<<NBUK, 256, 0, stream>>>(ebuf, bukBase, offsets, dis, csr_src);
    wt_kernel<<<24, 256, 0, stream>>>(Ws, wT);

    const int gemmGrid = NROWS / 64;      // 1563
    const int aggGrid = (NROWS / 64) * 8; // 12504
    // layer 0: f32 x -> lin planes ; agg -> bf16 hb (row-major)
    gemm_mfma<true><<<gemmGrid, 256, 0, stream>>>(x, wT, dis, lin);
    agg_kernel<false><<<aggGrid, 256, 0, stream>>>((const uint_t*)lin, offsets, csr_src, dis, bs, hb);
    // layer 1
    gemm_mfma<false><<<gemmGrid, 256, 0, stream>>>(hb, wT + 16384, dis, lin);
    agg_kernel<false><<<aggGrid, 256, 0, stream>>>((const uint_t*)lin, offsets, csr_src, dis, bs + DD, hb);
    // layer 2 -> f32 d_out
    gemm_mfma<false><<<gemmGrid, 256, 0, stream>>>(hb, wT + 32768, dis, lin);
    agg_kernel<true><<<aggGrid, 256, 0, stream>>>((const uint_t*)lin, offsets, csr_src, dis, bs + 2 * DD, d_out);
}

// Round 13
// 289.975 us; speedup vs baseline: 1.1692x; 1.1692x over previous
//
#include <hip/hip_runtime.h>
#include <hip/hip_bf16.h>

#define NN 100000
#define NROWS 100032      // NN rounded up to 64; rows >= NN are zero (gather sentinel)
#define NE 1600000
#define DD 128
#define NBUK 196          // ceil(100000 / 512) buckets of 512 target nodes
#define F1_BLOCKS 256
#define F3_BLOCKS 256

typedef unsigned short ushort_t;
typedef unsigned int uint_t;
typedef unsigned long long uint64_t_;
typedef __attribute__((ext_vector_type(8))) short bf16x8;
typedef __attribute__((ext_vector_type(4))) float f32x4;

__device__ __forceinline__ ushort_t bf16rne(float f) {
    uint_t u = __float_as_uint(f);
    u += 0x7FFF + ((u >> 16) & 1);
    return (ushort_t)(u >> 16);
}
__device__ __forceinline__ float bfLo(uint_t u) { return __uint_as_float(u << 16); }
__device__ __forceinline__ float bfHi(uint_t u) { return __uint_as_float(u & 0xFFFF0000u); }

// ---------------- CSR build (bucketed counting sort) ----------------

// f1 + wT prep fused: blocks [0,F1_BLOCKS) histogram; blocks >= F1_BLOCKS convert W.
__global__ __launch_bounds__(256) void f1_bucket_count(const int* __restrict__ col,
                                                       int* __restrict__ bukCount,
                                                       const float* __restrict__ Ws,
                                                       ushort_t* __restrict__ wT) {
    __shared__ int hist[NBUK];
    if (blockIdx.x >= F1_BLOCKS) {
        int idx = (blockIdx.x - F1_BLOCKS) * 256 + threadIdx.x;
        if (idx < 3 * 128 * 16) {
            int l = idx >> 11;
            int r = idx & 2047;
            int c = r >> 4;
            int kc = r & 15;
            const float* w = Ws + l * 16384;
            ushort_t tmp[8];
#pragma unroll
            for (int e = 0; e < 8; ++e)
                tmp[e] = bf16rne(w[(kc * 8 + e) * 128 + c]);
            *(uint4*)&wT[(size_t)l * 16384 + c * 128 + kc * 8] = *(uint4*)tmp;
        }
        return;
    }
    for (int t = threadIdx.x; t < NBUK; t += 256) hist[t] = 0;
    __syncthreads();
    const int epb = (NE + F1_BLOCKS - 1) / F1_BLOCKS;
    const int e0 = blockIdx.x * epb;
    const int e1 = min(e0 + epb, NE);
    for (int e = e0 + threadIdx.x; e < e1; e += 256)
        atomicAdd(&hist[col[e] >> 9], 1);
    __syncthreads();
    for (int t = threadIdx.x; t < NBUK; t += 256)
        if (hist[t]) atomicAdd(&bukCount[t], hist[t]);
}

__global__ void f2_bucket_scan(const int* __restrict__ bukCount,
                               int* __restrict__ bukBase,
                               int* __restrict__ bukCursor,
                               int* __restrict__ offsets) {
    __shared__ int s[256];
    const int t = threadIdx.x;
    int v = (t < NBUK) ? bukCount[t] : 0;
    s[t] = v;
    __syncthreads();
    for (int off = 1; off < 256; off <<= 1) {
        int tmp = (t >= off) ? s[t - off] : 0;
        __syncthreads();
        s[t] += tmp;
        __syncthreads();
    }
    int excl = s[t] - v;
    if (t < NBUK) { bukBase[t] = excl; bukCursor[t] = excl; }
    if (t == 255) { bukBase[NBUK] = s[255]; offsets[NN] = s[255]; }
}

// per-wave LDS histograms; ebuf packed as (row<<9)|col_local
__global__ __launch_bounds__(256) void f3_scatter(const int* __restrict__ row,
                                                  const int* __restrict__ col,
                                                  int* __restrict__ bukCursor,
                                                  int* __restrict__ ebuf) {
    __shared__ int hist[4][NBUK];
    __shared__ int base[4][NBUK];
    const int t = threadIdx.x;
    const int w = t >> 6;
    const int lane = t & 63;
    for (int i = t; i < 4 * NBUK; i += 256) (&hist[0][0])[i] = 0;
    __syncthreads();
    const int epb = (NE + F3_BLOCKS - 1) / F3_BLOCKS;
    const int e0 = blockIdx.x * epb;
    const int e1 = min(e0 + epb, NE);
    const int wepb = (e1 - e0 + 3) >> 2;
    const int we0 = e0 + w * wepb;
    const int we1 = min(we0 + wepb, e1);
    for (int e = we0 + lane; e < we1; e += 64)
        atomicAdd(&hist[w][col[e] >> 9], 1);
    __syncthreads();
    if (t < NBUK) {
        int h0 = hist[0][t], h1 = hist[1][t], h2 = hist[2][t], h3 = hist[3][t];
        int tot = h0 + h1 + h2 + h3;
        int g = tot ? atomicAdd(&bukCursor[t], tot) : 0;
        base[0][t] = g; base[1][t] = g + h0;
        base[2][t] = g + h0 + h1; base[3][t] = g + h0 + h1 + h2;
        hist[0][t] = 0; hist[1][t] = 0; hist[2][t] = 0; hist[3][t] = 0;
    }
    __syncthreads();
    for (int e = we0 + lane; e < we1; e += 64) {
        int c = col[e];
        int b = c >> 9;
        int r = atomicAdd(&hist[w][b], 1);
        ebuf[base[w][b] + r] = (row[e] << 9) | (c & 511);
    }
}

__global__ __launch_bounds__(256) void f4_finalize(const int* __restrict__ ebuf,
                                                   const int* __restrict__ bukBase,
                                                   int* __restrict__ offsets,
                                                   float* __restrict__ dis,
                                                   int* __restrict__ csr_src) {
    __shared__ int cnt[512];
    __shared__ int cur[512];
    __shared__ int s[256];
    const int t = threadIdx.x;
    const int colBase = blockIdx.x << 9;
    const int ncols = min(512, NN - colBase);
    cnt[t] = 0; cnt[t + 256] = 0;
    __syncthreads();
    const int eb0 = bukBase[blockIdx.x];
    const int eb1 = bukBase[blockIdx.x + 1];
    for (int e = eb0 + t; e < eb1; e += 256)
        atomicAdd(&cnt[ebuf[e] & 511], 1);
    __syncthreads();
    const int c0 = cnt[2 * t], c1 = cnt[2 * t + 1];
    const int psum = c0 + c1;
    s[t] = psum;
    __syncthreads();
    for (int off = 1; off < 256; off <<= 1) {
        int tmp = (t >= off) ? s[t - off] : 0;
        __syncthreads();
        s[t] += tmp;
        __syncthreads();
    }
    const int exclPair = s[t] - psum;
    const int g0 = eb0 + exclPair;
    const int g1 = g0 + c0;
    cur[2 * t] = g0; cur[2 * t + 1] = g1;
    if (2 * t < ncols)     { offsets[colBase + 2 * t]     = g0; dis[colBase + 2 * t]     = rsqrtf((float)(c0 + 1)); }
    if (2 * t + 1 < ncols) { offsets[colBase + 2 * t + 1] = g1; dis[colBase + 2 * t + 1] = rsqrtf((float)(c1 + 1)); }
    __syncthreads();
    for (int e = eb0 + t; e < eb1; e += 256) {
        int pc = ebuf[e];
        int p = atomicAdd(&cur[pc & 511], 1);
        csr_src[p] = pc >> 9;
    }
}

// ---------------- MFMA GEMM: Y[r][c] = bf16( (X@W)[r][c] * dis[r] ), row-major ----------------
// Rows >= NN are written as ZERO (gather sentinel rows for agg).
// Epilogue goes through LDS (reusing the W buffer) for wide coalesced stores.

template<bool XF32>
__global__ __launch_bounds__(256) void gemm_mfma(const void* __restrict__ Xv,
                                                 const ushort_t* __restrict__ wT,
                                                 const float* __restrict__ dis,
                                                 ushort_t* __restrict__ Y) {
    __shared__ short smem[128 * 136];   // 34.8 KB: W-stage, then bf16-C stage
    {
        const uint4* src = (const uint4*)wT;
        int t = threadIdx.x;
#pragma unroll
        for (int i = 0; i < 8; ++i) {
            int idx = i * 256 + t;
            int rowc = idx >> 4;
            int kc = idx & 15;
            uint4 v = src[idx];
            *(uint4*)&smem[rowc * 136 + kc * 8] = v;
        }
    }
    __syncthreads();

    const int wave = threadIdx.x >> 6;
    const int lane = threadIdx.x & 63;
    const int m = lane & 15;
    const int kg = lane >> 4;
    const int r0 = blockIdx.x * 64 + wave * 16;
    const int rowA = min(r0 + m, NN - 1);

    f32x4 acc[8];
#pragma unroll
    for (int ct = 0; ct < 8; ++ct) acc[ct] = (f32x4){0.f, 0.f, 0.f, 0.f};

#pragma unroll
    for (int ks = 0; ks < 4; ++ks) {
        bf16x8 af;
        if (XF32) {
            const float* xp = (const float*)Xv + (size_t)rowA * DD + ks * 32 + kg * 8;
            float4 f0 = *(const float4*)xp;
            float4 f1 = *(const float4*)(xp + 4);
            af[0] = (short)bf16rne(f0.x); af[1] = (short)bf16rne(f0.y);
            af[2] = (short)bf16rne(f0.z); af[3] = (short)bf16rne(f0.w);
            af[4] = (short)bf16rne(f1.x); af[5] = (short)bf16rne(f1.y);
            af[6] = (short)bf16rne(f1.z); af[7] = (short)bf16rne(f1.w);
        } else {
            const ushort_t* xp = (const ushort_t*)Xv + (size_t)rowA * DD + ks * 32 + kg * 8;
            af = *(const bf16x8*)xp;
        }
#pragma unroll
        for (int ct = 0; ct < 8; ++ct) {
            bf16x8 bf = *(const bf16x8*)&smem[(ct * 16 + m) * 136 + ks * 32 + kg * 8];
            acc[ct] = __builtin_amdgcn_mfma_f32_16x16x32_bf16(af, bf, acc[ct], 0, 0, 0);
        }
    }

    __syncthreads();   // all waves done reading W; smem becomes C-stage

    // C/D: col = ct*16 + m, row = kg*4 + rg  [m89-verified]
    ushort_t* sl = (ushort_t*)smem;          // [4 waves][16 rows][132 cols]
    const int rbase = r0 + kg * 4;
    float dv[4];
#pragma unroll
    for (int rg = 0; rg < 4; ++rg) dv[rg] = dis[min(rbase + rg, NN - 1)];
#pragma unroll
    for (int ct = 0; ct < 8; ++ct) {
#pragma unroll
        for (int rg = 0; rg < 4; ++rg)
            sl[(wave * 16 + kg * 4 + rg) * 132 + ct * 16 + m] = bf16rne(acc[ct][rg] * dv[rg]);
    }

    // read back row-major, store wide (wave covers contiguous 4 KB)
    const int lr = lane >> 2;        // 0..15: row within wave tile
    const int q  = lane & 3;         // 0..3: 32-ushort quarter
    const int grow = r0 + lr;
    const ushort_t* rb = sl + (wave * 16 + lr) * 132 + q * 32;
    uint2 d0 = *(const uint2*)(rb + 0);
    uint2 d1 = *(const uint2*)(rb + 4);
    uint2 d2 = *(const uint2*)(rb + 8);
    uint2 d3 = *(const uint2*)(rb + 12);
    uint2 d4 = *(const uint2*)(rb + 16);
    uint2 d5 = *(const uint2*)(rb + 20);
    uint2 d6 = *(const uint2*)(rb + 24);
    uint2 d7 = *(const uint2*)(rb + 28);
    const bool ok = grow < NN;
    uint4 v0 = ok ? make_uint4(d0.x, d0.y, d1.x, d1.y) : make_uint4(0, 0, 0, 0);
    uint4 v1 = ok ? make_uint4(d2.x, d2.y, d3.x, d3.y) : make_uint4(0, 0, 0, 0);
    uint4 v2 = ok ? make_uint4(d4.x, d4.y, d5.x, d5.y) : make_uint4(0, 0, 0, 0);
    uint4 v3 = ok ? make_uint4(d6.x, d6.y, d7.x, d7.y) : make_uint4(0, 0, 0, 0);
    uint4* yp = (uint4*)&Y[(size_t)grow * DD + q * 32];
    yp[0] = v0; yp[1] = v1; yp[2] = v2; yp[3] = v3;
}

// ---------------- aggregation (XCD-aware D-split, sentinel-padded, 128B/edge) ----------------
// Block = 4 waves; wave = 2 nodes x 64 dims (one D-half). 12.8 MB working set per half.
// Lanes with no edge use sentinel source NN (a zero row) -> no inner predication.

template<bool F32OUT>
__global__ __launch_bounds__(256) void agg_kernel(const uint_t* __restrict__ lin2,
                                                  const int* __restrict__ offsets,
                                                  const int* __restrict__ csr_src,
                                                  const float* __restrict__ dis,
                                                  const float* __restrict__ bias,
                                                  void* __restrict__ outv) {
    const int bid = blockIdx.x;                 // 25000 blocks
    const int xcd = bid & 7;
    const int h   = (xcd >> 2);                 // D-half 0/1
    const int g   = (bid >> 3) * 4 + (xcd & 3); // node-group of 8
    const int w    = threadIdx.x >> 6;
    const int lane = threadIdx.x & 63;
    const int l32  = lane & 31;
    const int hi   = lane >> 5;
    const int v = g * 8 + w * 2 + hi;

    const int start = offsets[v];
    const int end   = offsets[v + 1];
    const int n     = end - start;
    const int nvm   = n < 32 ? n : 32;

    int idxv = NN;                              // sentinel: zero row
    if (l32 < nvm) idxv = csr_src[start + l32];

    const int nv_other = __shfl(nvm, lane ^ 32);
    int kmax = nvm > nv_other ? nvm : nv_other;
    kmax = (kmax + 15) & ~15;                   // round to 16 (sentinels absorb padding)

    const uint_t doff = (uint_t)(h * 32 + l32); // uint index within row
    const float dv = dis[v];
    uint_t self = lin2[((uint_t)v << 6) | doff];
    float2 b    = ((const float2*)bias)[doff];

    float accx = 0.f, accy = 0.f;
    const int sbase = (lane & 32);
    for (int k = 0; k < kmax; k += 16) {
        int s0 = __shfl(idxv, sbase + k + 0);
        int s1 = __shfl(idxv, sbase + k + 1);
        int s2 = __shfl(idxv, sbase + k + 2);
        int s3 = __shfl(idxv, sbase + k + 3);
        int s4 = __shfl(idxv, sbase + k + 4);
        int s5 = __shfl(idxv, sbase + k + 5);
        int s6 = __shfl(idxv, sbase + k + 6);
        int s7 = __shfl(idxv, sbase + k + 7);
        int s8 = __shfl(idxv, sbase + k + 8);
        int s9 = __shfl(idxv, sbase + k + 9);
        int sa = __shfl(idxv, sbase + k + 10);
        int sb = __shfl(idxv, sbase + k + 11);
        int sc = __shfl(idxv, sbase + k + 12);
        int sd = __shfl(idxv, sbase + k + 13);
        int se = __shfl(idxv, sbase + k + 14);
        int sf = __shfl(idxv, sbase + k + 15);
        uint_t a0 = lin2[((uint_t)s0 << 6) | doff];
        uint_t a1 = lin2[((uint_t)s1 << 6) | doff];
        uint_t a2 = lin2[((uint_t)s2 << 6) | doff];
        uint_t a3 = lin2[((uint_t)s3 << 6) | doff];
        uint_t a4 = lin2[((uint_t)s4 << 6) | doff];
        uint_t a5 = lin2[((uint_t)s5 << 6) | doff];
        uint_t a6 = lin2[((uint_t)s6 << 6) | doff];
        uint_t a7 = lin2[((uint_t)s7 << 6) | doff];
        uint_t a8 = lin2[((uint_t)s8 << 6) | doff];
        uint_t a9 = lin2[((uint_t)s9 << 6) | doff];
        uint_t aa = lin2[((uint_t)sa << 6) | doff];
        uint_t ab = lin2[((uint_t)sb << 6) | doff];
        uint_t ac = lin2[((uint_t)sc << 6) | doff];
        uint_t ad = lin2[((uint_t)sd << 6) | doff];
        uint_t ae = lin2[((uint_t)se << 6) | doff];
        uint_t af = lin2[((uint_t)sf << 6) | doff];
        accx += bfLo(a0) + bfLo(a1) + bfLo(a2) + bfLo(a3)
              + bfLo(a4) + bfLo(a5) + bfLo(a6) + bfLo(a7)
              + bfLo(a8) + bfLo(a9) + bfLo(aa) + bfLo(ab)
              + bfLo(ac) + bfLo(ad) + bfLo(ae) + bfLo(af);
        accy += bfHi(a0) + bfHi(a1) + bfHi(a2) + bfHi(a3)
              + bfHi(a4) + bfHi(a5) + bfHi(a6) + bfHi(a7)
              + bfHi(a8) + bfHi(a9) + bfHi(aa) + bfHi(ab)
              + bfHi(ac) + bfHi(ad) + bfHi(ae) + bfHi(af);
    }
    // rare deg>32 tail
    for (int e = start + 32; e < end; ++e) {
        uint_t s = (uint_t)csr_src[e];
        uint_t a = lin2[(s << 6) | doff];
        accx += bfLo(a); accy += bfHi(a);
    }

    float rx = fmaxf(dv * (accx + bfLo(self)) + b.x, 0.f);
    float ry = fmaxf(dv * (accy + bfHi(self)) + b.y, 0.f);
    const size_t oidx = (size_t)v * 64 + doff;
    if (F32OUT) {
        float2 o = make_float2(rx, ry);
        __builtin_nontemporal_store(*(const uint64_t_*)&o, (uint64_t_*)((float2*)outv + oidx));
    } else {
        uint_t pk = (uint_t)bf16rne(rx) | ((uint_t)bf16rne(ry) << 16);
        __builtin_nontemporal_store(pk, (uint_t*)outv + oidx);
    }
}

// ---------------- launch ----------------

extern "C" void kernel_launch(void* const* d_in, const int* in_sizes, int n_in,
                              void* d_out, int out_size, void* d_ws, size_t ws_size,
                              hipStream_t stream) {
    const float* x   = (const float*)d_in[0];
    const int*   ei  = (const int*)d_in[1];
    const float* Ws  = (const float*)d_in[2];
    const float* bs  = (const float*)d_in[3];

    const int* row = ei;
    const int* col = ei + NE;

    char* ws = (char*)d_ws;
    // lin: NROWS*256 B = 25,608,192 (rows >= NN are zero sentinels; ebuf aliases low part)
    ushort_t* lin    = (ushort_t*)(ws + 0);
    int*   ebuf      = (int*)  (ws + 0);          // 6,400,000 B packed (dead before gemm)
    ushort_t* hb     = (ushort_t*)(ws + 25608192);// 25,600,000 B bf16 inter-layer h
    float* dis       = (float*)(ws + 51208192);   // 400,000 B
    int*   offsets   = (int*)  (ws + 51608192);   // 400,004 B
    int*   csr_src   = (int*)  (ws + 52008208);   // 6,400,000 B
    int*   bukCount  = (int*)  (ws + 58408208);   // 784 B
    int*   bukBase   = (int*)  (ws + 58409008);   // 788 B
    int*   bukCursor = (int*)  (ws + 58409808);   // 784 B
    ushort_t* wT     = (ushort_t*)(ws + 58410608);// 98,304 B

    (void)hipMemsetAsync(bukCount, 0, NBUK * sizeof(int), stream);
    f1_bucket_count<<<F1_BLOCKS + 24, 256, 0, stream>>>(col, bukCount, Ws, wT);
    f2_bucket_scan<<<1, 256, 0, stream>>>(bukCount, bukBase, bukCursor, offsets);
    f3_scatter<<<F3_BLOCKS, 256, 0, stream>>>(row, col, bukCursor, ebuf);
    f4_finalize<<<NBUK, 256, 0, stream>>>(ebuf, bukBase, offsets, dis, csr_src);

    const int gemmGrid = NROWS / 64;   // 1563
    const int aggGrid = (NN / 8) * 2;  // 25000
    // layer 0: f32 x -> lin ; agg -> bf16 hb
    gemm_mfma<true><<<gemmGrid, 256, 0, stream>>>(x, wT, dis, lin);
    agg_kernel<false><<<aggGrid, 256, 0, stream>>>((const uint_t*)lin, offsets, csr_src, dis, bs, hb);
    // layer 1
    gemm_mfma<false><<<gemmGrid, 256, 0, stream>>>(hb, wT + 16384, dis, lin);
    agg_kernel<false><<<aggGrid, 256, 0, stream>>>((const uint_t*)lin, offsets, csr_src, dis, bs + DD, hb);
    // layer 2 -> f32 d_out
    gemm_mfma<false><<<gemmGrid, 256, 0, stream>>>(hb, wT + 32768, dis, lin);
    agg_kernel<true><<<aggGrid, 256, 0, stream>>>((const uint_t*)lin, offsets, csr_src, dis, bs + 2 * DD, d_out);
}

// Round 14
// 280.750 us; speedup vs baseline: 1.2076x; 1.0329x over previous
//
#include <hip/hip_runtime.h>
#include <hip/hip_bf16.h>

#define NN 100000
#define NROWS 100032      // NN rounded up to 64; rows >= NN are zero (gather sentinel)
#define NE 1600000
#define DD 128
#define NBUK 196          // ceil(100000 / 512) buckets of 512 target nodes
#define BCAP 9216         // fixed bucket capacity: mean 8192, sigma ~90 -> +11 sigma
#define F3_BLOCKS 256

typedef unsigned short ushort_t;
typedef unsigned int uint_t;
typedef unsigned long long uint64_t_;
typedef __attribute__((ext_vector_type(8))) short bf16x8;
typedef __attribute__((ext_vector_type(4))) float f32x4;

__device__ __forceinline__ ushort_t bf16rne(float f) {
    uint_t u = __float_as_uint(f);
    u += 0x7FFF + ((u >> 16) & 1);
    return (ushort_t)(u >> 16);
}
__device__ __forceinline__ float bfLo(uint_t u) { return __uint_as_float(u << 16); }
__device__ __forceinline__ float bfHi(uint_t u) { return __uint_as_float(u & 0xFFFF0000u); }

// ---------------- CSR build (fixed-capacity bucketed counting sort) ----------------

// f3 + wT prep fused. Blocks [0,F3_BLOCKS): per-wave LDS hist -> claim range in
// bucket b's fixed region [b*BCAP ...) -> scatter packed (row<<9)|col_local.
// bukCnt accumulates per-bucket totals (scanned later by f2).
__global__ __launch_bounds__(256) void f3_scatter(const int* __restrict__ row,
                                                  const int* __restrict__ col,
                                                  int* __restrict__ bukCnt,
                                                  int* __restrict__ ebuf,
                                                  const float* __restrict__ Ws,
                                                  ushort_t* __restrict__ wT) {
    __shared__ int hist[4][NBUK];
    __shared__ int base[4][NBUK];
    if (blockIdx.x >= F3_BLOCKS) {
        int idx = (blockIdx.x - F3_BLOCKS) * 256 + threadIdx.x;
        if (idx < 3 * 128 * 16) {
            int l = idx >> 11;
            int r = idx & 2047;
            int c = r >> 4;
            int kc = r & 15;
            const float* w = Ws + l * 16384;
            ushort_t tmp[8];
#pragma unroll
            for (int e = 0; e < 8; ++e)
                tmp[e] = bf16rne(w[(kc * 8 + e) * 128 + c]);
            *(uint4*)&wT[(size_t)l * 16384 + c * 128 + kc * 8] = *(uint4*)tmp;
        }
        return;
    }
    const int t = threadIdx.x;
    const int w = t >> 6;
    const int lane = t & 63;
    for (int i = t; i < 4 * NBUK; i += 256) (&hist[0][0])[i] = 0;
    __syncthreads();
    const int epb = (NE + F3_BLOCKS - 1) / F3_BLOCKS;
    const int e0 = blockIdx.x * epb;
    const int e1 = min(e0 + epb, NE);
    const int wepb = (e1 - e0 + 3) >> 2;
    const int we0 = e0 + w * wepb;
    const int we1 = min(we0 + wepb, e1);
    for (int e = we0 + lane; e < we1; e += 64)
        atomicAdd(&hist[w][col[e] >> 9], 1);
    __syncthreads();
    if (t < NBUK) {
        int h0 = hist[0][t], h1 = hist[1][t], h2 = hist[2][t], h3 = hist[3][t];
        int tot = h0 + h1 + h2 + h3;
        int g = tot ? (t * BCAP + atomicAdd(&bukCnt[t], tot)) : 0;
        base[0][t] = g; base[1][t] = g + h0;
        base[2][t] = g + h0 + h1; base[3][t] = g + h0 + h1 + h2;
        hist[0][t] = 0; hist[1][t] = 0; hist[2][t] = 0; hist[3][t] = 0;
    }
    __syncthreads();
    for (int e = we0 + lane; e < we1; e += 64) {
        int c = col[e];
        int b = c >> 9;
        int r = atomicAdd(&hist[w][b], 1);
        ebuf[base[w][b] + r] = (row[e] << 9) | (c & 511);
    }
}

// f2: exclusive scan of bucket counts -> global compact bases; offsets[NN] = E.
__global__ void f2_bucket_scan(const int* __restrict__ bukCnt,
                               int* __restrict__ bukBase,
                               int* __restrict__ offsets) {
    __shared__ int s[256];
    const int t = threadIdx.x;
    int v = (t < NBUK) ? bukCnt[t] : 0;
    s[t] = v;
    __syncthreads();
    for (int off = 1; off < 256; off <<= 1) {
        int tmp = (t >= off) ? s[t - off] : 0;
        __syncthreads();
        s[t] += tmp;
        __syncthreads();
    }
    int excl = s[t] - v;
    if (t < NBUK) bukBase[t] = excl;
    if (t == 255) { bukBase[NBUK] = s[255]; offsets[NN] = s[255]; }
}

// f4: per bucket, LDS count+scan -> offsets + dis, then LDS-cursor scatter of
// csr_src into the bucket's compact global region.
__global__ __launch_bounds__(256) void f4_finalize(const int* __restrict__ ebuf,
                                                   const int* __restrict__ bukBase,
                                                   int* __restrict__ offsets,
                                                   float* __restrict__ dis,
                                                   int* __restrict__ csr_src) {
    __shared__ int cnt[512];
    __shared__ int cur[512];
    __shared__ int s[256];
    const int t = threadIdx.x;
    const int colBase = blockIdx.x << 9;
    const int ncols = min(512, NN - colBase);
    cnt[t] = 0; cnt[t + 256] = 0;
    __syncthreads();
    const int gb0 = bukBase[blockIdx.x];
    const int bcnt = bukBase[blockIdx.x + 1] - gb0;
    const int cap0 = blockIdx.x * BCAP;
    for (int e = cap0 + t; e < cap0 + bcnt; e += 256)
        atomicAdd(&cnt[ebuf[e] & 511], 1);
    __syncthreads();
    const int c0 = cnt[2 * t], c1 = cnt[2 * t + 1];
    const int psum = c0 + c1;
    s[t] = psum;
    __syncthreads();
    for (int off = 1; off < 256; off <<= 1) {
        int tmp = (t >= off) ? s[t - off] : 0;
        __syncthreads();
        s[t] += tmp;
        __syncthreads();
    }
    const int exclPair = s[t] - psum;
    const int g0 = gb0 + exclPair;
    const int g1 = g0 + c0;
    cur[2 * t] = g0; cur[2 * t + 1] = g1;
    if (2 * t < ncols)     { offsets[colBase + 2 * t]     = g0; dis[colBase + 2 * t]     = rsqrtf((float)(c0 + 1)); }
    if (2 * t + 1 < ncols) { offsets[colBase + 2 * t + 1] = g1; dis[colBase + 2 * t + 1] = rsqrtf((float)(c1 + 1)); }
    __syncthreads();
    for (int e = cap0 + t; e < cap0 + bcnt; e += 256) {
        int pc = ebuf[e];
        int p = atomicAdd(&cur[pc & 511], 1);
        csr_src[p] = pc >> 9;
    }
}

// ---------------- MFMA GEMM: Y[r][c] = bf16( (X@W)[r][c] * dis[r] ), row-major ----------------
// Block = 256 rows (4 waves x 4 tiles x 16 rows). W staged in LDS once, B-fragments
// then hoisted into registers (128 VGPR) -> the 4 row-tiles reuse them with NO LDS
// B-reads and NO cross-wave syncs (C-stage is wave-private LDS).
// Rows in [NN, NROWS) are written as ZERO (gather sentinel rows for agg).

template<bool XF32>
__global__ __launch_bounds__(256) void gemm_mfma(const void* __restrict__ Xv,
                                                 const ushort_t* __restrict__ wT,
                                                 const float* __restrict__ dis,
                                                 ushort_t* __restrict__ Y) {
    __shared__ short smem[128 * 136];   // 34.8 KB: W-stage, then per-wave C stage
    {
        const uint4* src = (const uint4*)wT;
        int t = threadIdx.x;
#pragma unroll
        for (int i = 0; i < 8; ++i) {
            int idx = i * 256 + t;
            int rowc = idx >> 4;
            int kc = idx & 15;
            uint4 v = src[idx];
            *(uint4*)&smem[rowc * 136 + kc * 8] = v;
        }
    }
    __syncthreads();

    const int wave = threadIdx.x >> 6;
    const int lane = threadIdx.x & 63;
    const int m = lane & 15;
    const int kg = lane >> 4;

    // hoist B fragments to registers (reused by all 4 tiles)
    bf16x8 bfr[8][4];
#pragma unroll
    for (int ct = 0; ct < 8; ++ct)
#pragma unroll
        for (int ks = 0; ks < 4; ++ks)
            bfr[ct][ks] = *(const bf16x8*)&smem[(ct * 16 + m) * 136 + ks * 32 + kg * 8];
    __syncthreads();   // all waves done reading W; smem becomes C-stage

    ushort_t* cs = (ushort_t*)smem + wave * (16 * 132);   // wave-private C region

#pragma unroll
    for (int rt = 0; rt < 4; ++rt) {
        const int r0 = blockIdx.x * 256 + rt * 64 + wave * 16;
        const int rowA = min(r0 + m, NN - 1);

        f32x4 acc[8];
#pragma unroll
        for (int ct = 0; ct < 8; ++ct) acc[ct] = (f32x4){0.f, 0.f, 0.f, 0.f};

#pragma unroll
        for (int ks = 0; ks < 4; ++ks) {
            bf16x8 af;
            if (XF32) {
                const float* xp = (const float*)Xv + (size_t)rowA * DD + ks * 32 + kg * 8;
                float4 f0 = *(const float4*)xp;
                float4 f1 = *(const float4*)(xp + 4);
                af[0] = (short)bf16rne(f0.x); af[1] = (short)bf16rne(f0.y);
                af[2] = (short)bf16rne(f0.z); af[3] = (short)bf16rne(f0.w);
                af[4] = (short)bf16rne(f1.x); af[5] = (short)bf16rne(f1.y);
                af[6] = (short)bf16rne(f1.z); af[7] = (short)bf16rne(f1.w);
            } else {
                const ushort_t* xp = (const ushort_t*)Xv + (size_t)rowA * DD + ks * 32 + kg * 8;
                af = *(const bf16x8*)xp;
            }
#pragma unroll
            for (int ct = 0; ct < 8; ++ct)
                acc[ct] = __builtin_amdgcn_mfma_f32_16x16x32_bf16(af, bfr[ct][ks], acc[ct], 0, 0, 0);
        }

        // C/D: col = ct*16 + m, row = kg*4 + rg  [m89-verified]; wave-private stage
        const int rbase = r0 + kg * 4;
        float dvv[4];
#pragma unroll
        for (int rg = 0; rg < 4; ++rg) dvv[rg] = dis[min(rbase + rg, NN - 1)];
#pragma unroll
        for (int ct = 0; ct < 8; ++ct) {
#pragma unroll
            for (int rg = 0; rg < 4; ++rg)
                cs[(kg * 4 + rg) * 132 + ct * 16 + m] = bf16rne(acc[ct][rg] * dvv[rg]);
        }

        // wave-local readback (lgkmcnt ordering within the wave), wide store
        const int lr = lane >> 2;        // 0..15: row within wave tile
        const int q  = lane & 3;         // 0..3: 32-ushort quarter
        const int grow = r0 + lr;
        const ushort_t* rb = cs + lr * 132 + q * 32;
        uint2 d0 = *(const uint2*)(rb + 0);
        uint2 d1 = *(const uint2*)(rb + 4);
        uint2 d2 = *(const uint2*)(rb + 8);
        uint2 d3 = *(const uint2*)(rb + 12);
        uint2 d4 = *(const uint2*)(rb + 16);
        uint2 d5 = *(const uint2*)(rb + 20);
        uint2 d6 = *(const uint2*)(rb + 24);
        uint2 d7 = *(const uint2*)(rb + 28);
        if (grow < NROWS) {
            const bool ok = grow < NN;
            uint4 v0 = ok ? make_uint4(d0.x, d0.y, d1.x, d1.y) : make_uint4(0, 0, 0, 0);
            uint4 v1 = ok ? make_uint4(d2.x, d2.y, d3.x, d3.y) : make_uint4(0, 0, 0, 0);
            uint4 v2 = ok ? make_uint4(d4.x, d4.y, d5.x, d5.y) : make_uint4(0, 0, 0, 0);
            uint4 v3 = ok ? make_uint4(d6.x, d6.y, d7.x, d7.y) : make_uint4(0, 0, 0, 0);
            uint4* yp = (uint4*)&Y[(size_t)grow * DD + q * 32];
            yp[0] = v0; yp[1] = v1; yp[2] = v2; yp[3] = v3;
        }
    }
}

// ---------------- aggregation (XCD-aware D-split, sentinel-padded, 128B/edge) ----------------
// Block = 4 waves; wave = 2 nodes x 64 dims (one D-half). 12.8 MB working set per half.
// Lanes with no edge use sentinel source NN (a zero row) -> no inner predication.

template<bool F32OUT>
__global__ __launch_bounds__(256) void agg_kernel(const uint_t* __restrict__ lin2,
                                                  const int* __restrict__ offsets,
                                                  const int* __restrict__ csr_src,
                                                  const float* __restrict__ dis,
                                                  const float* __restrict__ bias,
                                                  void* __restrict__ outv) {
    const int bid = blockIdx.x;                 // 25000 blocks
    const int xcd = bid & 7;
    const int h   = (xcd >> 2);                 // D-half 0/1
    const int g   = (bid >> 3) * 4 + (xcd & 3); // node-group of 8
    const int w    = threadIdx.x >> 6;
    const int lane = threadIdx.x & 63;
    const int l32  = lane & 31;
    const int hi   = lane >> 5;
    const int v = g * 8 + w * 2 + hi;

    const int start = offsets[v];
    const int end   = offsets[v + 1];
    const int n     = end - start;
    const int nvm   = n < 32 ? n : 32;

    int idxv = NN;                              // sentinel: zero row
    if (l32 < nvm) idxv = csr_src[start + l32];

    const int nv_other = __shfl(nvm, lane ^ 32);
    int kmax = nvm > nv_other ? nvm : nv_other;
    kmax = (kmax + 15) & ~15;                   // round to 16 (sentinels absorb padding)

    const uint_t doff = (uint_t)(h * 32 + l32); // uint index within row
    const float dv = dis[v];
    uint_t self = lin2[((uint_t)v << 6) | doff];
    float2 b    = ((const float2*)bias)[doff];

    float accx = 0.f, accy = 0.f;
    const int sbase = (lane & 32);
    for (int k = 0; k < kmax; k += 16) {
        int s0 = __shfl(idxv, sbase + k + 0);
        int s1 = __shfl(idxv, sbase + k + 1);
        int s2 = __shfl(idxv, sbase + k + 2);
        int s3 = __shfl(idxv, sbase + k + 3);
        int s4 = __shfl(idxv, sbase + k + 4);
        int s5 = __shfl(idxv, sbase + k + 5);
        int s6 = __shfl(idxv, sbase + k + 6);
        int s7 = __shfl(idxv, sbase + k + 7);
        int s8 = __shfl(idxv, sbase + k + 8);
        int s9 = __shfl(idxv, sbase + k + 9);
        int sa = __shfl(idxv, sbase + k + 10);
        int sb = __shfl(idxv, sbase + k + 11);
        int sc = __shfl(idxv, sbase + k + 12);
        int sd = __shfl(idxv, sbase + k + 13);
        int se = __shfl(idxv, sbase + k + 14);
        int sf = __shfl(idxv, sbase + k + 15);
        uint_t a0 = lin2[((uint_t)s0 << 6) | doff];
        uint_t a1 = lin2[((uint_t)s1 << 6) | doff];
        uint_t a2 = lin2[((uint_t)s2 << 6) | doff];
        uint_t a3 = lin2[((uint_t)s3 << 6) | doff];
        uint_t a4 = lin2[((uint_t)s4 << 6) | doff];
        uint_t a5 = lin2[((uint_t)s5 << 6) | doff];
        uint_t a6 = lin2[((uint_t)s6 << 6) | doff];
        uint_t a7 = lin2[((uint_t)s7 << 6) | doff];
        uint_t a8 = lin2[((uint_t)s8 << 6) | doff];
        uint_t a9 = lin2[((uint_t)s9 << 6) | doff];
        uint_t aa = lin2[((uint_t)sa << 6) | doff];
        uint_t ab = lin2[((uint_t)sb << 6) | doff];
        uint_t ac = lin2[((uint_t)sc << 6) | doff];
        uint_t ad = lin2[((uint_t)sd << 6) | doff];
        uint_t ae = lin2[((uint_t)se << 6) | doff];
        uint_t af = lin2[((uint_t)sf << 6) | doff];
        accx += bfLo(a0) + bfLo(a1) + bfLo(a2) + bfLo(a3)
              + bfLo(a4) + bfLo(a5) + bfLo(a6) + bfLo(a7)
              + bfLo(a8) + bfLo(a9) + bfLo(aa) + bfLo(ab)
              + bfLo(ac) + bfLo(ad) + bfLo(ae) + bfLo(af);
        accy += bfHi(a0) + bfHi(a1) + bfHi(a2) + bfHi(a3)
              + bfHi(a4) + bfHi(a5) + bfHi(a6) + bfHi(a7)
              + bfHi(a8) + bfHi(a9) + bfHi(aa) + bfHi(ab)
              + bfHi(ac) + bfHi(ad) + bfHi(ae) + bfHi(af);
    }
    // rare deg>32 tail
    for (int e = start + 32; e < end; ++e) {
        uint_t s = (uint_t)csr_src[e];
        uint_t a = lin2[(s << 6) | doff];
        accx += bfLo(a); accy += bfHi(a);
    }

    float rx = fmaxf(dv * (accx + bfLo(self)) + b.x, 0.f);
    float ry = fmaxf(dv * (accy + bfHi(self)) + b.y, 0.f);
    const size_t oidx = (size_t)v * 64 + doff;
    if (F32OUT) {
        float2 o = make_float2(rx, ry);
        __builtin_nontemporal_store(*(const uint64_t_*)&o, (uint64_t_*)((float2*)outv + oidx));
    } else {
        uint_t pk = (uint_t)bf16rne(rx) | ((uint_t)bf16rne(ry) << 16);
        __builtin_nontemporal_store(pk, (uint_t*)outv + oidx);
    }
}

// ---------------- launch ----------------

extern "C" void kernel_launch(void* const* d_in, const int* in_sizes, int n_in,
                              void* d_out, int out_size, void* d_ws, size_t ws_size,
                              hipStream_t stream) {
    const float* x   = (const float*)d_in[0];
    const int*   ei  = (const int*)d_in[1];
    const float* Ws  = (const float*)d_in[2];
    const float* bs  = (const float*)d_in[3];

    const int* row = ei;
    const int* col = ei + NE;

    char* ws = (char*)d_ws;
    // lin: NROWS*256 B = 25,608,192 (rows >= NN are zero sentinels; ebuf aliases low part)
    ushort_t* lin    = (ushort_t*)(ws + 0);
    int*   ebuf      = (int*)  (ws + 0);          // 196*9216*4 = 7,225,344 B (dead before gemm)
    ushort_t* hb     = (ushort_t*)(ws + 25608192);// 25,600,000 B bf16 inter-layer h
    float* dis       = (float*)(ws + 51208192);   // 400,000 B
    int*   offsets   = (int*)  (ws + 51608192);   // 400,004 B
    int*   csr_src   = (int*)  (ws + 52008208);   // 6,400,000 B
    int*   bukCnt    = (int*)  (ws + 58408208);   // 784 B
    int*   bukBase   = (int*)  (ws + 58409008);   // 788 B
    ushort_t* wT     = (ushort_t*)(ws + 58410608);// 98,304 B

    (void)hipMemsetAsync(bukCnt, 0, NBUK * sizeof(int), stream);
    f3_scatter<<<F3_BLOCKS + 24, 256, 0, stream>>>(row, col, bukCnt, ebuf, Ws, wT);
    f2_bucket_scan<<<1, 256, 0, stream>>>(bukCnt, bukBase, offsets);
    f4_finalize<<<NBUK, 256, 0, stream>>>(ebuf, bukBase, offsets, dis, csr_src);

    const int gemmGrid = (NROWS + 255) / 256;   // 391
    const int aggGrid = (NN / 8) * 2;           // 25000
    // layer 0: f32 x -> lin ; agg -> bf16 hb
    gemm_mfma<true><<<gemmGrid, 256, 0, stream>>>(x, wT, dis, lin);
    agg_kernel<false><<<aggGrid, 256, 0, stream>>>((const uint_t*)lin, offsets, csr_src, dis, bs, hb);
    // layer 1
    gemm_mfma<false><<<gemmGrid, 256, 0, stream>>>(hb, wT + 16384, dis, lin);
    agg_kernel<false><<<aggGrid, 256, 0, stream>>>((const uint_t*)lin, offsets, csr_src, dis, bs + DD, hb);
    // layer 2 -> f32 d_out
    gemm_mfma<false><<<gemmGrid, 256, 0, stream>>>(hb, wT + 32768, dis, lin);
    agg_kernel<true><<<aggGrid, 256, 0, stream>>>((const uint_t*)lin, offsets, csr_src, dis, bs + 2 * DD, d_out);
}

// Round 15
// 273.962 us; speedup vs baseline: 1.2375x; 1.0248x over previous
//
#include <hip/hip_runtime.h>
#include <hip/hip_bf16.h>

#define NN 100000
#define NROWS 100032      // NN rounded up to 64; rows >= NN are zero (gather sentinel)
#define NE 1600000
#define DD 128
#define NBUK 196          // ceil(100000 / 512) buckets of 512 target nodes
#define BCAP 9216         // fixed bucket capacity: mean 8192, sigma ~90 -> +11 sigma
#define F3_BLOCKS 256

typedef unsigned short ushort_t;
typedef unsigned int uint_t;
typedef unsigned long long uint64_t_;
typedef __attribute__((ext_vector_type(8))) short bf16x8;
typedef __attribute__((ext_vector_type(4))) float f32x4;

__device__ __forceinline__ ushort_t bf16rne(float f) {
    uint_t u = __float_as_uint(f);
    u += 0x7FFF + ((u >> 16) & 1);
    return (ushort_t)(u >> 16);
}
__device__ __forceinline__ float bfLo(uint_t u) { return __uint_as_float(u << 16); }
__device__ __forceinline__ float bfHi(uint_t u) { return __uint_as_float(u & 0xFFFF0000u); }

// ---------------- CSR build (fixed-capacity bucketed counting sort) ----------------

// f3 + wT prep fused. Blocks [0,F3_BLOCKS): per-wave LDS hist -> claim range in
// bucket b's fixed region [b*BCAP ...) -> scatter packed (row<<9)|col_local.
__global__ __launch_bounds__(256) void f3_scatter(const int* __restrict__ row,
                                                  const int* __restrict__ col,
                                                  int* __restrict__ bukCnt,
                                                  int* __restrict__ ebuf,
                                                  const float* __restrict__ Ws,
                                                  ushort_t* __restrict__ wT) {
    __shared__ int hist[4][NBUK];
    __shared__ int base[4][NBUK];
    if (blockIdx.x >= F3_BLOCKS) {
        int idx = (blockIdx.x - F3_BLOCKS) * 256 + threadIdx.x;
        if (idx < 3 * 128 * 16) {
            int l = idx >> 11;
            int r = idx & 2047;
            int c = r >> 4;
            int kc = r & 15;
            const float* w = Ws + l * 16384;
            ushort_t tmp[8];
#pragma unroll
            for (int e = 0; e < 8; ++e)
                tmp[e] = bf16rne(w[(kc * 8 + e) * 128 + c]);
            *(uint4*)&wT[(size_t)l * 16384 + c * 128 + kc * 8] = *(uint4*)tmp;
        }
        return;
    }
    const int t = threadIdx.x;
    const int w = t >> 6;
    const int lane = t & 63;
    for (int i = t; i < 4 * NBUK; i += 256) (&hist[0][0])[i] = 0;
    __syncthreads();
    const int epb = (NE + F3_BLOCKS - 1) / F3_BLOCKS;
    const int e0 = blockIdx.x * epb;
    const int e1 = min(e0 + epb, NE);
    const int wepb = (e1 - e0 + 3) >> 2;
    const int we0 = e0 + w * wepb;
    const int we1 = min(we0 + wepb, e1);
    for (int e = we0 + lane; e < we1; e += 64)
        atomicAdd(&hist[w][col[e] >> 9], 1);
    __syncthreads();
    if (t < NBUK) {
        int h0 = hist[0][t], h1 = hist[1][t], h2 = hist[2][t], h3 = hist[3][t];
        int tot = h0 + h1 + h2 + h3;
        int g = tot ? (t * BCAP + atomicAdd(&bukCnt[t], tot)) : 0;
        base[0][t] = g; base[1][t] = g + h0;
        base[2][t] = g + h0 + h1; base[3][t] = g + h0 + h1 + h2;
        hist[0][t] = 0; hist[1][t] = 0; hist[2][t] = 0; hist[3][t] = 0;
    }
    __syncthreads();
    for (int e = we0 + lane; e < we1; e += 64) {
        int c = col[e];
        int b = c >> 9;
        int r = atomicAdd(&hist[w][b], 1);
        ebuf[base[w][b] + r] = (row[e] << 9) | (c & 511);
    }
}

// f4 (with f2's scan inlined): each block scans the 196 bucket counts itself to get
// its compact global base, then LDS count+scan -> offsets + dis, then scatter csr_src.
__global__ __launch_bounds__(256) void f4_finalize(const int* __restrict__ bukCnt,
                                                   const int* __restrict__ ebuf,
                                                   int* __restrict__ offsets,
                                                   float* __restrict__ dis,
                                                   int* __restrict__ csr_src) {
    __shared__ int cnt[512];
    __shared__ int cur[512];
    __shared__ int s[256];
    __shared__ int gb0_sh;
    const int t = threadIdx.x;

    // inline bucket scan (replaces f2): exclusive prefix at bucket blockIdx.x
    {
        int c = (t < NBUK) ? bukCnt[t] : 0;
        s[t] = c;
        __syncthreads();
        for (int off = 1; off < 256; off <<= 1) {
            int tmp = (t >= off) ? s[t - off] : 0;
            __syncthreads();
            s[t] += tmp;
            __syncthreads();
        }
        if (t == blockIdx.x) gb0_sh = s[t] - c;          // exclusive prefix
        if (blockIdx.x == 0 && t == NBUK - 1) offsets[NN] = s[t];  // total = E
        __syncthreads();
    }
    const int gb0  = gb0_sh;
    const int bcnt = bukCnt[blockIdx.x];

    const int colBase = blockIdx.x << 9;
    const int ncols = min(512, NN - colBase);
    cnt[t] = 0; cnt[t + 256] = 0;
    __syncthreads();
    const int cap0 = blockIdx.x * BCAP;
    for (int e = cap0 + t; e < cap0 + bcnt; e += 256)
        atomicAdd(&cnt[ebuf[e] & 511], 1);
    __syncthreads();
    const int c0 = cnt[2 * t], c1 = cnt[2 * t + 1];
    const int psum = c0 + c1;
    s[t] = psum;
    __syncthreads();
    for (int off = 1; off < 256; off <<= 1) {
        int tmp = (t >= off) ? s[t - off] : 0;
        __syncthreads();
        s[t] += tmp;
        __syncthreads();
    }
    const int exclPair = s[t] - psum;
    const int g0 = gb0 + exclPair;
    const int g1 = g0 + c0;
    cur[2 * t] = g0; cur[2 * t + 1] = g1;
    if (2 * t < ncols)     { offsets[colBase + 2 * t]     = g0; dis[colBase + 2 * t]     = rsqrtf((float)(c0 + 1)); }
    if (2 * t + 1 < ncols) { offsets[colBase + 2 * t + 1] = g1; dis[colBase + 2 * t + 1] = rsqrtf((float)(c1 + 1)); }
    __syncthreads();
    for (int e = cap0 + t; e < cap0 + bcnt; e += 256) {
        int pc = ebuf[e];
        int p = atomicAdd(&cur[pc & 511], 1);
        csr_src[p] = pc >> 9;
    }
}

// ---------------- MFMA GEMM: Y[r][c] = bf16( (X@W)[r][c] * dis[r] ), row-major ----------------
// Block = 256 rows (4 waves x 4 tiles x 16 rows). W staged in LDS once, B-fragments
// hoisted to registers; per-tile A-fragments for tile rt+1 are prefetched BEFORE tile
// rt's LDS C-stage so the global-load latency hides under the epilogue.
// Rows in [NN, NROWS) are written as ZERO (gather sentinel rows for agg).

template<bool XF32>
__global__ __launch_bounds__(256) void gemm_mfma(const void* __restrict__ Xv,
                                                 const ushort_t* __restrict__ wT,
                                                 const float* __restrict__ dis,
                                                 ushort_t* __restrict__ Y) {
    __shared__ short smem[128 * 136];   // 34.8 KB: W-stage, then per-wave C stage
    {
        const uint4* src = (const uint4*)wT;
        int t = threadIdx.x;
#pragma unroll
        for (int i = 0; i < 8; ++i) {
            int idx = i * 256 + t;
            int rowc = idx >> 4;
            int kc = idx & 15;
            uint4 v = src[idx];
            *(uint4*)&smem[rowc * 136 + kc * 8] = v;
        }
    }
    __syncthreads();

    const int wave = threadIdx.x >> 6;
    const int lane = threadIdx.x & 63;
    const int m = lane & 15;
    const int kg = lane >> 4;

    // hoist B fragments to registers (reused by all 4 tiles)
    bf16x8 bfr[8][4];
#pragma unroll
    for (int ct = 0; ct < 8; ++ct)
#pragma unroll
        for (int ks = 0; ks < 4; ++ks)
            bfr[ct][ks] = *(const bf16x8*)&smem[(ct * 16 + m) * 136 + ks * 32 + kg * 8];
    __syncthreads();   // all waves done reading W; smem becomes C-stage

    ushort_t* cs = (ushort_t*)smem + wave * (16 * 132);   // wave-private C region

    auto loadA = [&](int rowA_, bf16x8 af[4]) {
#pragma unroll
        for (int ks = 0; ks < 4; ++ks) {
            if (XF32) {
                const float* xp = (const float*)Xv + (size_t)rowA_ * DD + ks * 32 + kg * 8;
                float4 f0 = *(const float4*)xp;
                float4 f1 = *(const float4*)(xp + 4);
                bf16x8 a;
                a[0] = (short)bf16rne(f0.x); a[1] = (short)bf16rne(f0.y);
                a[2] = (short)bf16rne(f0.z); a[3] = (short)bf16rne(f0.w);
                a[4] = (short)bf16rne(f1.x); a[5] = (short)bf16rne(f1.y);
                a[6] = (short)bf16rne(f1.z); a[7] = (short)bf16rne(f1.w);
                af[ks] = a;
            } else {
                af[ks] = *(const bf16x8*)((const ushort_t*)Xv + (size_t)rowA_ * DD + ks * 32 + kg * 8);
            }
        }
    };

    const int rbb = blockIdx.x * 256 + wave * 16;
    bf16x8 afc[4], afn[4];
    loadA(min(rbb + m, NN - 1), afc);

#pragma unroll
    for (int rt = 0; rt < 4; ++rt) {
        const int r0 = rbb + rt * 64;

        f32x4 acc[8];
#pragma unroll
        for (int ct = 0; ct < 8; ++ct) acc[ct] = (f32x4){0.f, 0.f, 0.f, 0.f};

#pragma unroll
        for (int ks = 0; ks < 4; ++ks)
#pragma unroll
            for (int ct = 0; ct < 8; ++ct)
                acc[ct] = __builtin_amdgcn_mfma_f32_16x16x32_bf16(afc[ks], bfr[ct][ks], acc[ct], 0, 0, 0);

        // prefetch next tile's A-fragments BEFORE the C-stage (hides load latency)
        if (rt < 3) loadA(min(r0 + 64 + m, NN - 1), afn);

        // C/D: col = ct*16 + m, row = kg*4 + rg  [m89-verified]; wave-private stage
        const int rbase = r0 + kg * 4;
        float dvv[4];
#pragma unroll
        for (int rg = 0; rg < 4; ++rg) dvv[rg] = dis[min(rbase + rg, NN - 1)];
#pragma unroll
        for (int ct = 0; ct < 8; ++ct) {
#pragma unroll
            for (int rg = 0; rg < 4; ++rg)
                cs[(kg * 4 + rg) * 132 + ct * 16 + m] = bf16rne(acc[ct][rg] * dvv[rg]);
        }

        // wave-local readback, wide store
        const int lr = lane >> 2;        // 0..15: row within wave tile
        const int q  = lane & 3;         // 0..3: 32-ushort quarter
        const int grow = r0 + lr;
        const ushort_t* rb = cs + lr * 132 + q * 32;
        uint2 d0 = *(const uint2*)(rb + 0);
        uint2 d1 = *(const uint2*)(rb + 4);
        uint2 d2 = *(const uint2*)(rb + 8);
        uint2 d3 = *(const uint2*)(rb + 12);
        uint2 d4 = *(const uint2*)(rb + 16);
        uint2 d5 = *(const uint2*)(rb + 20);
        uint2 d6 = *(const uint2*)(rb + 24);
        uint2 d7 = *(const uint2*)(rb + 28);
        if (grow < NROWS) {
            const bool ok = grow < NN;
            uint4 v0 = ok ? make_uint4(d0.x, d0.y, d1.x, d1.y) : make_uint4(0, 0, 0, 0);
            uint4 v1 = ok ? make_uint4(d2.x, d2.y, d3.x, d3.y) : make_uint4(0, 0, 0, 0);
            uint4 v2 = ok ? make_uint4(d4.x, d4.y, d5.x, d5.y) : make_uint4(0, 0, 0, 0);
            uint4 v3 = ok ? make_uint4(d6.x, d6.y, d7.x, d7.y) : make_uint4(0, 0, 0, 0);
            uint4* yp = (uint4*)&Y[(size_t)grow * DD + q * 32];
            yp[0] = v0; yp[1] = v1; yp[2] = v2; yp[3] = v3;
        }

#pragma unroll
        for (int ks = 0; ks < 4; ++ks) afc[ks] = afn[ks];
    }
}

// ---------------- aggregation (XCD-aware D-split, sentinel-padded, 128B/edge) ----------------
// Block = 4 waves; wave = 2 nodes x 64 dims (one D-half). 12.8 MB working set per half.
// Lanes with no edge use sentinel source NN (a zero row) -> no inner predication.

template<bool F32OUT>
__global__ __launch_bounds__(256) void agg_kernel(const uint_t* __restrict__ lin2,
                                                  const int* __restrict__ offsets,
                                                  const int* __restrict__ csr_src,
                                                  const float* __restrict__ dis,
                                                  const float* __restrict__ bias,
                                                  void* __restrict__ outv) {
    const int bid = blockIdx.x;                 // 25000 blocks
    const int xcd = bid & 7;
    const int h   = (xcd >> 2);                 // D-half 0/1
    const int g   = (bid >> 3) * 4 + (xcd & 3); // node-group of 8
    const int w    = threadIdx.x >> 6;
    const int lane = threadIdx.x & 63;
    const int l32  = lane & 31;
    const int hi   = lane >> 5;
    const int v = g * 8 + w * 2 + hi;

    const int start = offsets[v];
    const int end   = offsets[v + 1];
    const int n     = end - start;
    const int nvm   = n < 32 ? n : 32;

    int idxv = NN;                              // sentinel: zero row
    if (l32 < nvm) idxv = csr_src[start + l32];

    const int nv_other = __shfl(nvm, lane ^ 32);
    int kmax = nvm > nv_other ? nvm : nv_other;
    kmax = (kmax + 15) & ~15;                   // round to 16 (sentinels absorb padding)

    const uint_t doff = (uint_t)(h * 32 + l32); // uint index within row
    const float dv = dis[v];
    uint_t self = lin2[((uint_t)v << 6) | doff];
    float2 b    = ((const float2*)bias)[doff];

    float accx = 0.f, accy = 0.f;
    const int sbase = (lane & 32);
    for (int k = 0; k < kmax; k += 16) {
        int s0 = __shfl(idxv, sbase + k + 0);
        int s1 = __shfl(idxv, sbase + k + 1);
        int s2 = __shfl(idxv, sbase + k + 2);
        int s3 = __shfl(idxv, sbase + k + 3);
        int s4 = __shfl(idxv, sbase + k + 4);
        int s5 = __shfl(idxv, sbase + k + 5);
        int s6 = __shfl(idxv, sbase + k + 6);
        int s7 = __shfl(idxv, sbase + k + 7);
        int s8 = __shfl(idxv, sbase + k + 8);
        int s9 = __shfl(idxv, sbase + k + 9);
        int sa = __shfl(idxv, sbase + k + 10);
        int sb = __shfl(idxv, sbase + k + 11);
        int sc = __shfl(idxv, sbase + k + 12);
        int sd = __shfl(idxv, sbase + k + 13);
        int se = __shfl(idxv, sbase + k + 14);
        int sf = __shfl(idxv, sbase + k + 15);
        uint_t a0 = lin2[((uint_t)s0 << 6) | doff];
        uint_t a1 = lin2[((uint_t)s1 << 6) | doff];
        uint_t a2 = lin2[((uint_t)s2 << 6) | doff];
        uint_t a3 = lin2[((uint_t)s3 << 6) | doff];
        uint_t a4 = lin2[((uint_t)s4 << 6) | doff];
        uint_t a5 = lin2[((uint_t)s5 << 6) | doff];
        uint_t a6 = lin2[((uint_t)s6 << 6) | doff];
        uint_t a7 = lin2[((uint_t)s7 << 6) | doff];
        uint_t a8 = lin2[((uint_t)s8 << 6) | doff];
        uint_t a9 = lin2[((uint_t)s9 << 6) | doff];
        uint_t aa = lin2[((uint_t)sa << 6) | doff];
        uint_t ab = lin2[((uint_t)sb << 6) | doff];
        uint_t ac = lin2[((uint_t)sc << 6) | doff];
        uint_t ad = lin2[((uint_t)sd << 6) | doff];
        uint_t ae = lin2[((uint_t)se << 6) | doff];
        uint_t af = lin2[((uint_t)sf << 6) | doff];
        accx += bfLo(a0) + bfLo(a1) + bfLo(a2) + bfLo(a3)
              + bfLo(a4) + bfLo(a5) + bfLo(a6) + bfLo(a7)
              + bfLo(a8) + bfLo(a9) + bfLo(aa) + bfLo(ab)
              + bfLo(ac) + bfLo(ad) + bfLo(ae) + bfLo(af);
        accy += bfHi(a0) + bfHi(a1) + bfHi(a2) + bfHi(a3)
              + bfHi(a4) + bfHi(a5) + bfHi(a6) + bfHi(a7)
              + bfHi(a8) + bfHi(a9) + bfHi(aa) + bfHi(ab)
              + bfHi(ac) + bfHi(ad) + bfHi(ae) + bfHi(af);
    }
    // rare deg>32 tail
    for (int e = start + 32; e < end; ++e) {
        uint_t s = (uint_t)csr_src[e];
        uint_t a = lin2[(s << 6) | doff];
        accx += bfLo(a); accy += bfHi(a);
    }

    float rx = fmaxf(dv * (accx + bfLo(self)) + b.x, 0.f);
    float ry = fmaxf(dv * (accy + bfHi(self)) + b.y, 0.f);
    const size_t oidx = (size_t)v * 64 + doff;
    if (F32OUT) {
        float2 o = make_float2(rx, ry);
        __builtin_nontemporal_store(*(const uint64_t_*)&o, (uint64_t_*)((float2*)outv + oidx));
    } else {
        uint_t pk = (uint_t)bf16rne(rx) | ((uint_t)bf16rne(ry) << 16);
        __builtin_nontemporal_store(pk, (uint_t*)outv + oidx);
    }
}

// ---------------- launch ----------------

extern "C" void kernel_launch(void* const* d_in, const int* in_sizes, int n_in,
                              void* d_out, int out_size, void* d_ws, size_t ws_size,
                              hipStream_t stream) {
    const float* x   = (const float*)d_in[0];
    const int*   ei  = (const int*)d_in[1];
    const float* Ws  = (const float*)d_in[2];
    const float* bs  = (const float*)d_in[3];

    const int* row = ei;
    const int* col = ei + NE;

    char* ws = (char*)d_ws;
    // lin: NROWS*256 B = 25,608,192 (rows >= NN are zero sentinels; ebuf aliases low part)
    ushort_t* lin    = (ushort_t*)(ws + 0);
    int*   ebuf      = (int*)  (ws + 0);          // 196*9216*4 = 7,225,344 B (dead before gemm)
    ushort_t* hb     = (ushort_t*)(ws + 25608192);// 25,600,000 B bf16 inter-layer h
    float* dis       = (float*)(ws + 51208192);   // 400,000 B
    int*   offsets   = (int*)  (ws + 51608192);   // 400,004 B
    int*   csr_src   = (int*)  (ws + 52008208);   // 6,400,000 B
    int*   bukCnt    = (int*)  (ws + 58408208);   // 784 B
    ushort_t* wT     = (ushort_t*)(ws + 58410608);// 98,304 B

    (void)hipMemsetAsync(bukCnt, 0, NBUK * sizeof(int), stream);
    f3_scatter<<<F3_BLOCKS + 24, 256, 0, stream>>>(row, col, bukCnt, ebuf, Ws, wT);
    f4_finalize<<<NBUK, 256, 0, stream>>>(bukCnt, ebuf, offsets, dis, csr_src);

    const int gemmGrid = (NROWS + 255) / 256;   // 391
    const int aggGrid = (NN / 8) * 2;           // 25000
    // layer 0: f32 x -> lin ; agg -> bf16 hb
    gemm_mfma<true><<<gemmGrid, 256, 0, stream>>>(x, wT, dis, lin);
    agg_kernel<false><<<aggGrid, 256, 0, stream>>>((const uint_t*)lin, offsets, csr_src, dis, bs, hb);
    // layer 1
    gemm_mfma<false><<<gemmGrid, 256, 0, stream>>>(hb, wT + 16384, dis, lin);
    agg_kernel<false><<<aggGrid, 256, 0, stream>>>((const uint_t*)lin, offsets, csr_src, dis, bs + DD, hb);
    // layer 2 -> f32 d_out
    gemm_mfma<false><<<gemmGrid, 256, 0, stream>>>(hb, wT + 32768, dis, lin);
    agg_kernel<true><<<aggGrid, 256, 0, stream>>>((const uint_t*)lin, offsets, csr_src, dis, bs + 2 * DD, d_out);
}